// Round 1
// baseline (750.153 us; speedup 1.0000x reference)
//
#include <hip/hip_runtime.h>
#include <math.h>

#define NTOT   32768
#define NSCN   16
#define NPS    2048
#define KK     16
#define CD     128
#define HD     256

// ---------------------------------------------------------------------------
// Kernel 1: exact KNN (stable top-k semantics) + Gaussian kernel weights.
// 256 blocks x 256 threads. Block b: 128 points [ (b&15)*128 , +128 ) of scene b>>4.
// Thread t: point pair-index t>>1, candidate half t&1 (j in [half*1024, +1024)).
// Even lane merges odd partner's sorted list (partner indices are all larger,
// so strict-< insertion preserves jax.lax.top_k stable tie-breaking).
// ---------------------------------------------------------------------------
__global__ __launch_bounds__(256) void knn_kernel(
    const float* __restrict__ pos,
    int* __restrict__ idx_out, float* __restrict__ ker_out, float* __restrict__ den_out)
{
    __shared__ float2 sp[NPS];
    const int b = blockIdx.x;
    const int scene = b >> 4;
    const int sbase = scene * NPS;
    const float2* gp = (const float2*)pos + sbase;
    for (int t = threadIdx.x; t < NPS; t += 256) sp[t] = gp[t];
    __syncthreads();

    const int lp    = (b & 15) * 128 + (threadIdx.x >> 1);  // local point id in scene
    const int half  = threadIdx.x & 1;
    const int jbase = half * (NPS / 2);

    const float2 my = sp[lp];
    float dk[KK]; int ik[KK];
#pragma unroll
    for (int s = 0; s < KK; ++s) { dk[s] = 3.0e38f; ik[s] = 0; }

    float2 nx = sp[jbase];
    for (int jj = 0; jj < NPS / 2; ++jj) {
        const float2 cur = nx;
        nx = sp[jbase + ((jj + 1) & (NPS / 2 - 1))];        // prefetch next
        const float dx = cur.x - my.x;
        const float dy = cur.y - my.y;
        // bit-exact vs reference: mul,mul,add in f32, NO fma contraction
        const float d2 = __fadd_rn(__fmul_rn(dx, dx), __fmul_rn(dy, dy));
        if (d2 < dk[KK - 1]) {
            float cd = d2; int ci = jbase + jj;
#pragma unroll
            for (int s = 0; s < KK; ++s) {
                const bool sm = cd < dk[s];
                const float od = dk[s]; const int oi = ik[s];
                dk[s] = sm ? cd : od;  ik[s] = sm ? ci : oi;
                cd    = sm ? od : cd;  ci    = sm ? oi : ci;
            }
        }
    }

    // merge partner (odd half) into even lane's list
#pragma unroll
    for (int s = 0; s < KK; ++s) {
        const float pd = __shfl_xor(dk[s], 1);
        const int   pi = __shfl_xor(ik[s], 1);
        if (half == 0 && pd < dk[KK - 1]) {
            float cd = pd; int ci = pi;
#pragma unroll
            for (int r = 0; r < KK; ++r) {
                const bool sm = cd < dk[r];
                const float od = dk[r]; const int oi = ik[r];
                dk[r] = sm ? cd : od;  ik[r] = sm ? ci : oi;
                cd    = sm ? od : cd;  ci    = sm ? oi : ci;
            }
        }
    }

    if (half == 0) {
        const int gi = sbase + lp;
        float kv[KK];
        float den = 0.f;
#pragma unroll
        for (int s = 0; s < KK; ++s) { kv[s] = expf(-2.0f * dk[s]); den += kv[s]; }
        int4*   ip4 = (int4*)(idx_out + gi * KK);
        float4* kp4 = (float4*)(ker_out + gi * KK);
#pragma unroll
        for (int s = 0; s < 4; ++s) {
            ip4[s] = make_int4(sbase + ik[4*s], sbase + ik[4*s+1], sbase + ik[4*s+2], sbase + ik[4*s+3]);
            kp4[s] = make_float4(kv[4*s], kv[4*s+1], kv[4*s+2], kv[4*s+3]);
        }
        den_out[gi] = den;
    }
}

// 8-wide fma helpers (float4-based and float2-based rows)
#define FMA8(acc, s, ptr) { \
    const float4 _r0 = *(const float4*)(ptr); \
    const float4 _r1 = *(const float4*)((ptr) + 4); \
    acc[0] += (s)*_r0.x; acc[1] += (s)*_r0.y; acc[2] += (s)*_r0.z; acc[3] += (s)*_r0.w; \
    acc[4] += (s)*_r1.x; acc[5] += (s)*_r1.y; acc[6] += (s)*_r1.z; acc[7] += (s)*_r1.w; }

#define FMA16(acc, s, ptr) { \
    const float4 _r0 = *(const float4*)(ptr); \
    const float4 _r1 = *(const float4*)((ptr) + 4); \
    const float4 _r2 = *(const float4*)((ptr) + 8); \
    const float4 _r3 = *(const float4*)((ptr) + 12); \
    acc[0]  += (s)*_r0.x; acc[1]  += (s)*_r0.y; acc[2]  += (s)*_r0.z; acc[3]  += (s)*_r0.w; \
    acc[4]  += (s)*_r1.x; acc[5]  += (s)*_r1.y; acc[6]  += (s)*_r1.z; acc[7]  += (s)*_r1.w; \
    acc[8]  += (s)*_r2.x; acc[9]  += (s)*_r2.y; acc[10] += (s)*_r2.z; acc[11] += (s)*_r2.w; \
    acc[12] += (s)*_r3.x; acc[13] += (s)*_r3.y; acc[14] += (s)*_r3.z; acc[15] += (s)*_r3.w; }

#define FMA8_F2(acc, s, ptr) { \
    const float2 _a = *(const float2*)(ptr); \
    const float2 _b = *(const float2*)((ptr) + 2); \
    const float2 _c = *(const float2*)((ptr) + 4); \
    const float2 _d = *(const float2*)((ptr) + 6); \
    acc[0] += (s)*_a.x; acc[1] += (s)*_a.y; acc[2] += (s)*_b.x; acc[3] += (s)*_b.y; \
    acc[4] += (s)*_c.x; acc[5] += (s)*_c.y; acc[6] += (s)*_d.x; acc[7] += (s)*_d.y; }

// ---------------------------------------------------------------------------
// Kernel 2: agg = sum_k ker * w[idx], y = agg @ Wc + bc, LayerNorm -> yn
// Grid NTOT/16 blocks, 256 threads: thread (p = t>>4 point, q = t&15 colgroup of 8)
// ---------------------------------------------------------------------------
__global__ __launch_bounds__(256) void conv_ln_kernel(
    const float* __restrict__ w, const int* __restrict__ idx, const float* __restrict__ ker,
    const float* __restrict__ Wc, const float* __restrict__ bc,
    const float* __restrict__ gamma, const float* __restrict__ beta,
    float* __restrict__ yn)
{
    __shared__ float aggS[16][132];
    const int p = threadIdx.x >> 4, q = threadIdx.x & 15;
    const int i = blockIdx.x * 16 + p;
    const int c0 = q * 8;

    float acc[8];
#pragma unroll
    for (int e = 0; e < 8; ++e) acc[e] = 0.f;
    const int*   ip = idx + i * KK;
    const float* kp = ker + i * KK;
#pragma unroll 4
    for (int k = 0; k < KK; ++k) {
        const int j = ip[k];
        const float kv = kp[k];
        FMA8(acc, kv, w + j * CD + c0);
    }
    *(float4*)&aggS[p][c0]     = make_float4(acc[0], acc[1], acc[2], acc[3]);
    *(float4*)&aggS[p][c0 + 4] = make_float4(acc[4], acc[5], acc[6], acc[7]);
    __syncthreads();

    float y[8];
#pragma unroll
    for (int e = 0; e < 8; ++e) y[e] = bc[c0 + e];
    for (int k = 0; k < CD; k += 4) {
        const float4 av = *(const float4*)&aggS[p][k];
        const float* wr = Wc + k * CD + c0;
        FMA8(y, av.x, wr);
        FMA8(y, av.y, wr + CD);
        FMA8(y, av.z, wr + 2 * CD);
        FMA8(y, av.w, wr + 3 * CD);
    }
    // LayerNorm across the 16 q-lanes (128 channels)
    float s = 0.f;
#pragma unroll
    for (int e = 0; e < 8; ++e) s += y[e];
    s += __shfl_xor(s, 1); s += __shfl_xor(s, 2); s += __shfl_xor(s, 4); s += __shfl_xor(s, 8);
    const float mu = s * (1.f / 128.f);
    float v2 = 0.f;
#pragma unroll
    for (int e = 0; e < 8; ++e) { const float t = y[e] - mu; v2 += t * t; }
    v2 += __shfl_xor(v2, 1); v2 += __shfl_xor(v2, 2); v2 += __shfl_xor(v2, 4); v2 += __shfl_xor(v2, 8);
    const float rs = 1.f / sqrtf(v2 * (1.f / 128.f) + 1e-5f);
    float o[8];
#pragma unroll
    for (int e = 0; e < 8; ++e) o[e] = (y[e] - mu) * rs * gamma[c0 + e] + beta[c0 + e];
    *(float4*)(yn + i * CD + c0)     = make_float4(o[0], o[1], o[2], o[3]);
    *(float4*)(yn + i * CD + c0 + 4) = make_float4(o[4], o[5], o[6], o[7]);
}

// ---------------------------------------------------------------------------
// Kernel 3: sampled = (sum_k ker * yn[idx]) / den
// ---------------------------------------------------------------------------
__global__ __launch_bounds__(256) void sample_kernel(
    const float* __restrict__ yn, const int* __restrict__ idx, const float* __restrict__ ker,
    const float* __restrict__ den, float* __restrict__ outS)
{
    const int p = threadIdx.x >> 4, q = threadIdx.x & 15;
    const int i = blockIdx.x * 16 + p;
    const int c0 = q * 8;
    float acc[8];
#pragma unroll
    for (int e = 0; e < 8; ++e) acc[e] = 0.f;
    const int*   ip = idx + i * KK;
    const float* kp = ker + i * KK;
#pragma unroll 4
    for (int k = 0; k < KK; ++k) {
        const int j = ip[k];
        const float kv = kp[k];
        FMA8(acc, kv, yn + j * CD + c0);
    }
    const float dn = den[i];
    float o[8];
#pragma unroll
    for (int e = 0; e < 8; ++e) o[e] = acc[e] / dn;
    *(float4*)(outS + i * CD + c0)     = make_float4(o[0], o[1], o[2], o[3]);
    *(float4*)(outS + i * CD + c0 + 4) = make_float4(o[4], o[5], o[6], o[7]);
}

// ---------------------------------------------------------------------------
// Kernel 4: residual MLP: h = relu(w@W1+b1), delta = h@W2+b2 (130 cols),
// out_pos = pos + delta[:, :2], out_w = w + delta[:, 2:]
// thread (p,q): h cols q*16..+15 ; delta cols q*8..+7 ; cols 128/129 split-reduced
// ---------------------------------------------------------------------------
__global__ __launch_bounds__(256) void mlp_kernel(
    const float* __restrict__ w, const float* __restrict__ pos,
    const float* __restrict__ W1, const float* __restrict__ b1,
    const float* __restrict__ W2, const float* __restrict__ b2,
    float* __restrict__ out_pos, float* __restrict__ out_w)
{
    __shared__ float wS[16][132];
    __shared__ float hS[16][260];
    const int p = threadIdx.x >> 4, q = threadIdx.x & 15;
    const int i = blockIdx.x * 16 + p;

    {   // stage this block's 16 weight rows (coalesced)
        const float4 a = *(const float4*)(w + i * CD + q * 8);
        const float4 b = *(const float4*)(w + i * CD + q * 8 + 4);
        *(float4*)&wS[p][q * 8]     = a;
        *(float4*)&wS[p][q * 8 + 4] = b;
    }
    __syncthreads();

    // ---- h = relu(w @ W1 + b1), 16 cols per thread ----
    const int hc0 = q * 16;
    float h[16];
#pragma unroll
    for (int e = 0; e < 16; ++e) h[e] = b1[hc0 + e];
    for (int k = 0; k < CD; k += 4) {
        const float4 av = *(const float4*)&wS[p][k];
        const float* wr = W1 + k * HD + hc0;
        FMA16(h, av.x, wr);
        FMA16(h, av.y, wr + HD);
        FMA16(h, av.z, wr + 2 * HD);
        FMA16(h, av.w, wr + 3 * HD);
    }
#pragma unroll
    for (int e = 0; e < 16; ++e) h[e] = fmaxf(h[e], 0.f);
#pragma unroll
    for (int e = 0; e < 16; e += 4)
        *(float4*)&hS[p][hc0 + e] = make_float4(h[e], h[e + 1], h[e + 2], h[e + 3]);
    __syncthreads();

    // ---- delta = h @ W2 + b2 : cols q*8..q*8+7 (W2 row stride 130 -> float2 loads) ----
    const int c0 = q * 8;
    float d[8];
#pragma unroll
    for (int e = 0; e < 8; ++e) d[e] = b2[c0 + e];
    for (int k = 0; k < HD; k += 4) {
        const float4 hv = *(const float4*)&hS[p][k];
        const float* wr = W2 + k * 130 + c0;
        FMA8_F2(d, hv.x, wr);
        FMA8_F2(d, hv.y, wr + 130);
        FMA8_F2(d, hv.z, wr + 2 * 130);
        FMA8_F2(d, hv.w, wr + 3 * 130);
    }
    // ---- delta cols 128,129: k-range split across q then shfl reduce ----
    float s128 = 0.f, s129 = 0.f;
    {
        const int kb = q * 16;
#pragma unroll
        for (int k = 0; k < 16; ++k) {
            const float hv = hS[p][kb + k];
            s128 += hv * W2[(kb + k) * 130 + 128];
            s129 += hv * W2[(kb + k) * 130 + 129];
        }
        s128 += __shfl_xor(s128, 1); s128 += __shfl_xor(s128, 2);
        s128 += __shfl_xor(s128, 4); s128 += __shfl_xor(s128, 8);
        s129 += __shfl_xor(s129, 1); s129 += __shfl_xor(s129, 2);
        s129 += __shfl_xor(s129, 4); s129 += __shfl_xor(s129, 8);
    }

    if (q == 0) {
        const float2 pp = *(const float2*)(pos + i * 2);
        out_pos[i * 2 + 0] = pp.x + d[0];
        out_pos[i * 2 + 1] = pp.y + d[1];
#pragma unroll
        for (int e = 2; e < 8; ++e) out_w[i * CD + (e - 2)] = wS[p][e - 2] + d[e];
        out_w[i * CD + 126] = wS[p][126] + (s128 + b2[128]);
        out_w[i * CD + 127] = wS[p][127] + (s129 + b2[129]);
    } else {
        const int o0 = c0 - 2;
#pragma unroll
        for (int e = 0; e < 8; ++e) out_w[i * CD + o0 + e] = wS[p][o0 + e] + d[e];
    }
}

extern "C" void kernel_launch(void* const* d_in, const int* in_sizes, int n_in,
                              void* d_out, int out_size, void* d_ws, size_t ws_size,
                              hipStream_t stream)
{
    (void)in_sizes; (void)n_in; (void)out_size; (void)ws_size;
    const float* pos   = (const float*)d_in[0];
    const float* wts   = (const float*)d_in[1];
    // d_in[2] = batch (sorted, equal-sized) -> implicit: scene = i / 2048
    const float* Wc    = (const float*)d_in[3];
    const float* bc    = (const float*)d_in[4];
    const float* gamma = (const float*)d_in[5];
    const float* beta  = (const float*)d_in[6];
    const float* W1    = (const float*)d_in[7];
    const float* b1    = (const float*)d_in[8];
    const float* W2    = (const float*)d_in[9];
    const float* b2    = (const float*)d_in[10];

    float* out_pos = (float*)d_out;
    float* out_w   = out_pos + NTOT * 2;
    float* out_s   = out_w + NTOT * CD;

    // workspace: idx[N*K] int | ker[N*K] f32 | den[N] f32 | yn[N*C] f32  (~21 MB)
    int*   idxW = (int*)d_ws;
    float* kerW = (float*)d_ws + NTOT * KK;
    float* denW = kerW + NTOT * KK;
    float* ynW  = denW + NTOT;

    knn_kernel<<<256, 256, 0, stream>>>(pos, idxW, kerW, denW);
    conv_ln_kernel<<<NTOT / 16, 256, 0, stream>>>(wts, idxW, kerW, Wc, bc, gamma, beta, ynW);
    sample_kernel<<<NTOT / 16, 256, 0, stream>>>(ynW, idxW, kerW, denW, out_s);
    mlp_kernel<<<NTOT / 16, 256, 0, stream>>>(wts, pos, W1, b1, W2, b2, out_pos, out_w);
}